// Round 7
// baseline (183.483 us; speedup 1.0000x reference)
//
#include <hip/hip_runtime.h>

// Problem: B=64, S=128, D_MODEL=D_INNER=1024  ->  M = B*S = 8192, K = N = 1024.
// Reference simplifies: numerator/denominator == v exactly (dw>0, exp_k>0 cancel),
// so out = (sigmoid(emb@Wq+bq) * (emb@Wv+bv)) @ Wo + bo.  Wk, bk, w are dead inputs.
//
// R7: kill the embB intermediate (prep's 96 MB HBM round trip, ~20us). gemm_qv now
// reads emb fp32 directly: global->VGPR float4 loads, pack to bf16 via v_perm
// (round-half-up: +0x8000 then truncate ~= RNE), ds_write_b128 into the SAME
// swizzled LDS layout as R5 -> proven inner loop (0 bank conflicts) unchanged.
// prep = weight transposes only. bt unchanged (R6 128x128).

typedef short bf16x8 __attribute__((ext_vector_type(8)));  // 8 bf16 = 4 VGPRs
typedef float f32x4  __attribute__((ext_vector_type(4)));

__device__ __forceinline__ short f2bf(float f) {  // RNE fp32 -> bf16
  union { float f; unsigned u; } x; x.f = f;
  unsigned r = x.u + 0x7fffu + ((x.u >> 16) & 1u);
  return (short)(r >> 16);
}

// pack two fp32 -> bf16 pair (round-half-up), one v_perm after two v_add
__device__ __forceinline__ unsigned pkbf(float f0, float f1) {
  unsigned a = __float_as_uint(f1) + 0x8000u;  // src0: bytes 4-7 of {s0:s1}
  unsigned b = __float_as_uint(f0) + 0x8000u;  // src1: bytes 0-3
  return __builtin_amdgcn_perm(a, b, 0x07060302u);  // [f0.hi16 | f1.hi16]
}

struct alignas(16) S8 { short v[8]; };

__device__ __forceinline__ S8 pack8(float4 x, float4 y) {
  union { unsigned d[4]; S8 s; } u;
  u.d[0] = pkbf(x.x, x.y); u.d[1] = pkbf(x.z, x.w);
  u.d[2] = pkbf(y.x, y.y); u.d[3] = pkbf(y.z, y.w);
  return u.s;
}

#define GLDS(g, l) \
  __builtin_amdgcn_global_load_lds((const __attribute__((address_space(1))) void*)(g), \
                                   (__attribute__((address_space(3))) void*)(l), 16, 0, 0)

// ---- Phase 0: transpose+cast the three 1024x1024 weights (grid 3072, 1 tile/block) ----
__global__ __launch_bounds__(256) void prep_kernel(
    const float* __restrict__ Wq, const float* __restrict__ Wv, const float* __restrict__ Wo,
    short* __restrict__ WqvT, short* __restrict__ WoT) {
  __shared__ float tr[32 * 33];
  const int t = threadIdx.x;
  const int z = blockIdx.x;
  const float* in = (z < 1024) ? Wq : (z < 2048) ? Wv : Wo;
  short* op = (z < 1024) ? WqvT : (z < 2048) ? (WqvT + 1048576) : WoT;
  const int ti = z & 1023;
  const int bx = (ti & 31) * 32, by = (ti >> 5) * 32;
  const int tx = t & 31, ty = t >> 5;
#pragma unroll
  for (int i = 0; i < 32; i += 8)
    tr[(ty + i) * 33 + tx] = in[(size_t)(by + ty + i) * 1024 + bx + tx];
  __syncthreads();
#pragma unroll
  for (int i = 0; i < 32; i += 8)
    op[(size_t)(bx + ty + i) * 1024 + by + tx] = f2bf(tr[tx * 33 + ty + i]);
}

// ---- Phase 1: X = sigmoid(emb@WqT+bq) * (emb@WvT+bv), bf16. BK=64. ----
// Block 128x64, 4 waves of 64x32 (q and v). grid (64,16)=1024.
// A staged fp32->bf16 in-kernel (reg path); B staged via GLDS (bf16).
__global__ __launch_bounds__(256) void gemm_qv_kernel(
    const float* __restrict__ A,      // emb fp32 [8192][1024]
    const short* __restrict__ BT,     // [WqT|WvT] bf16 [2048][1024]
    const float* __restrict__ bq, const float* __restrict__ bv, short* __restrict__ X) {
  __shared__ short As[128 * 64];  // 16 KiB
  __shared__ short Bqs[64 * 64];  // 8 KiB
  __shared__ short Bvs[64 * 64];  // 8 KiB
  const int t = threadIdx.x;
  const int lane = t & 63;
  const int w = t >> 6;
  const int l16 = lane & 15;
  const int quad = lane >> 4;
  const int bm = blockIdx.x * 128;
  const int bn = blockIdx.y * 64;
  const int wm = (w & 1) * 64;
  const int wn = (w >> 1) * 32;

  // A staging (per-lane): thread owns bf16 chunk (row r8 + {0,32,64,96}, slot t&7),
  // holding global chunk ch = (t&7)^(r8&7)  [same swizzle as R5]
  const int r8 = t >> 3;
  const int ch = (t & 7) ^ (r8 & 7);
  const float* gA0 = A + (size_t)(bm + r8) * 1024 + ch * 8;
  const float* gA1 = gA0 + 32 * 1024;
  const float* gA2 = gA0 + 64 * 1024;
  const float* gA3 = gA0 + 96 * 1024;
  short* sA = As + r8 * 64 + (t & 7) * 8;  // per-lane ds_write dest (scatter OK)

  // B staging via GLDS (wave-uniform LDS base)
  const int swe = ((t & 7) ^ (r8 & 7)) * 8;
  const short* pBq0 = BT + (size_t)(bn + r8) * 1024 + swe;
  const short* pBq1 = pBq0 + 32 * 1024;
  const short* pBv0 = BT + (size_t)(1024 + bn + r8) * 1024 + swe;
  const short* pBv1 = pBv0 + 32 * 1024;
  short* lBq = Bqs + w * 512;
  short* lBv = Bvs + w * 512;

  // fragment bases (loop-invariant; i handled by ds imm offsets)
  const int qsw0 = (quad ^ (l16 & 7)) * 8;        // k-half 0: chunk quad
  const int qsw1 = ((quad + 4) ^ (l16 & 7)) * 8;  // k-half 1: chunk quad+4
  const short* fA0 = As + (wm + l16) * 64 + qsw0;
  const short* fA1 = As + (wm + l16) * 64 + qsw1;
  const short* fq0 = Bqs + (wn + l16) * 64 + qsw0;
  const short* fq1 = Bqs + (wn + l16) * 64 + qsw1;
  const short* fv0 = Bvs + (wn + l16) * 64 + qsw0;
  const short* fv1 = Bvs + (wn + l16) * 64 + qsw1;

  f32x4 accq[4][2] = {};
  f32x4 accv[4][2] = {};

  for (int it = 0; it < 16; ++it) {
    // A: fp32 global -> regs (issue all loads first, overlap with B GLDS)
    float4 a0 = *(const float4*)(gA0);     float4 a0b = *(const float4*)(gA0 + 4);
    float4 a1 = *(const float4*)(gA1);     float4 a1b = *(const float4*)(gA1 + 4);
    float4 a2 = *(const float4*)(gA2);     float4 a2b = *(const float4*)(gA2 + 4);
    float4 a3 = *(const float4*)(gA3);     float4 a3b = *(const float4*)(gA3 + 4);
    GLDS(pBq0, lBq); GLDS(pBq1, lBq + 2048);
    GLDS(pBv0, lBv); GLDS(pBv1, lBv + 2048);
    // pack + ds_write (same LDS layout as R5)
    *(S8*)(sA)        = pack8(a0, a0b);
    *(S8*)(sA + 2048) = pack8(a1, a1b);
    *(S8*)(sA + 4096) = pack8(a2, a2b);
    *(S8*)(sA + 6144) = pack8(a3, a3b);
    gA0 += 64; gA1 += 64; gA2 += 64; gA3 += 64;
    pBq0 += 64; pBq1 += 64; pBv0 += 64; pBv1 += 64;
    __syncthreads();

#pragma unroll
    for (int h = 0; h < 2; h++) {
      const short* fA = h ? fA1 : fA0;
      const short* fq = h ? fq1 : fq0;
      const short* fv = h ? fv1 : fv0;
      bf16x8 av[4], bqf[2], bvf[2];
#pragma unroll
      for (int i = 0; i < 4; i++) av[i] = *(const bf16x8*)(fA + i * 1024);
#pragma unroll
      for (int j = 0; j < 2; j++) {
        bqf[j] = *(const bf16x8*)(fq + j * 1024);
        bvf[j] = *(const bf16x8*)(fv + j * 1024);
      }
#pragma unroll
      for (int i = 0; i < 4; i++)
#pragma unroll
        for (int j = 0; j < 2; j++) {
          accq[i][j] = __builtin_amdgcn_mfma_f32_16x16x32_bf16(av[i], bqf[j], accq[i][j], 0, 0, 0);
          accv[i][j] = __builtin_amdgcn_mfma_f32_16x16x32_bf16(av[i], bvf[j], accv[i][j], 0, 0, 0);
        }
    }
    __syncthreads();
  }

  // epilogue: C/D layout col=lane&15, row=(lane>>4)*4+reg  [m89/m91-verified]
#pragma unroll
  for (int j = 0; j < 2; j++) {
    int col = bn + wn + j * 16 + l16;
    float bql = bq[col], bvl = bv[col];
#pragma unroll
    for (int i = 0; i < 4; i++)
#pragma unroll
      for (int r = 0; r < 4; r++) {
        int row = bm + wm + i * 16 + quad * 4 + r;
        float q = accq[i][j][r] + bql;
        float v = accv[i][j][r] + bvl;
        float s = 1.0f / (1.0f + __expf(-q));
        X[(size_t)row * 1024 + col] = f2bf(s * v);
      }
  }
}

// ---- Phase 2: out = X @ WoT^T + bo, fp32. 128x128 tile, BK=64, grid (64,8). ----
__global__ __launch_bounds__(256) void gemm_bt_kernel(
    const short* __restrict__ A, const short* __restrict__ BT, float* __restrict__ C,
    const float* __restrict__ bias) {
  __shared__ short As[128 * 64];  // 16 KiB
  __shared__ short Bs[128 * 64];  // 16 KiB
  const int t = threadIdx.x;
  const int lane = t & 63;
  const int w = t >> 6;
  const int l16 = lane & 15;
  const int quad = lane >> 4;
  const int bm = blockIdx.x * 128;
  const int bn = blockIdx.y * 128;
  const int wm = (w & 1) * 64;
  const int wn = (w >> 1) * 64;

  const int r8 = t >> 3;
  const int swe = ((t & 7) ^ (r8 & 7)) * 8;
  const short* pA0 = A + (size_t)(bm + r8) * 1024 + swe;
  const short* pA1 = pA0 + 32 * 1024;
  const short* pA2 = pA0 + 64 * 1024;
  const short* pA3 = pA0 + 96 * 1024;
  const short* pB0 = BT + (size_t)(bn + r8) * 1024 + swe;
  const short* pB1 = pB0 + 32 * 1024;
  const short* pB2 = pB0 + 64 * 1024;
  const short* pB3 = pB0 + 96 * 1024;
  short* lA = As + w * 512;
  short* lB = Bs + w * 512;

  const int qsw0 = (quad ^ (l16 & 7)) * 8;
  const int qsw1 = ((quad + 4) ^ (l16 & 7)) * 8;
  const short* fA0 = As + (wm + l16) * 64 + qsw0;
  const short* fA1 = As + (wm + l16) * 64 + qsw1;
  const short* fB0 = Bs + (wn + l16) * 64 + qsw0;
  const short* fB1 = Bs + (wn + l16) * 64 + qsw1;

  f32x4 acc[4][4] = {};

  for (int it = 0; it < 16; ++it) {
    GLDS(pA0, lA); GLDS(pA1, lA + 2048); GLDS(pA2, lA + 4096); GLDS(pA3, lA + 6144);
    GLDS(pB0, lB); GLDS(pB1, lB + 2048); GLDS(pB2, lB + 4096); GLDS(pB3, lB + 6144);
    pA0 += 64; pA1 += 64; pA2 += 64; pA3 += 64;
    pB0 += 64; pB1 += 64; pB2 += 64; pB3 += 64;
    __syncthreads();

#pragma unroll
    for (int h = 0; h < 2; h++) {
      const short* fA = h ? fA1 : fA0;
      const short* fB = h ? fB1 : fB0;
      bf16x8 av[4], bw[4];
#pragma unroll
      for (int i = 0; i < 4; i++) av[i] = *(const bf16x8*)(fA + i * 1024);
#pragma unroll
      for (int j = 0; j < 4; j++) bw[j] = *(const bf16x8*)(fB + j * 1024);
#pragma unroll
      for (int i = 0; i < 4; i++)
#pragma unroll
        for (int j = 0; j < 4; j++)
          acc[i][j] = __builtin_amdgcn_mfma_f32_16x16x32_bf16(av[i], bw[j], acc[i][j], 0, 0, 0);
    }
    __syncthreads();
  }

#pragma unroll
  for (int j = 0; j < 4; j++) {
    int col = bn + wn + j * 16 + l16;
    float bl = bias[col];
#pragma unroll
    for (int i = 0; i < 4; i++)
#pragma unroll
      for (int r = 0; r < 4; r++) {
        int row = bm + wm + i * 16 + quad * 4 + r;
        C[(size_t)row * 1024 + col] = acc[i][j][r] + bl;
      }
  }
}

extern "C" void kernel_launch(void* const* d_in, const int* in_sizes, int n_in,
                              void* d_out, int out_size, void* d_ws, size_t ws_size,
                              hipStream_t stream) {
  const float* emb = (const float*)d_in[0];
  const float* Wq  = (const float*)d_in[1];
  const float* bq  = (const float*)d_in[2];
  // d_in[3]=Wk, d_in[4]=bk, d_in[7]=w are mathematically dead (they cancel)
  const float* Wv  = (const float*)d_in[5];
  const float* bv  = (const float*)d_in[6];
  const float* Wo  = (const float*)d_in[8];
  const float* bo  = (const float*)d_in[9];
  float* out = (float*)d_out;

  // workspace layout (bytes)
  char* ws = (char*)d_ws;
  short* X    = (short*)(ws);                 // 8192*1024 bf16 = 16 MiB
  short* WqvT = (short*)(ws + 16777216);      // [WqT | WvT] 2048*1024 = 4 MiB
  short* WoT  = (short*)(ws + 20971520);      // 1024*1024 = 2 MiB
  // total: 23,068,672 bytes

  prep_kernel<<<3072, 256, 0, stream>>>(Wq, Wv, Wo, WqvT, WoT);
  gemm_qv_kernel<<<dim3(64, 16), 256, 0, stream>>>(emb, WqvT, bq, bv, X);
  gemm_bt_kernel<<<dim3(64, 8), 256, 0, stream>>>(X, WoT, out, bo);
}

// Round 8
// 183.184 us; speedup vs baseline: 1.0016x; 1.0016x over previous
//
#include <hip/hip_runtime.h>

// Problem: B=64, S=128, D_MODEL=D_INNER=1024  ->  M = B*S = 8192, K = N = 1024.
// Reference simplifies: numerator/denominator == v exactly (dw>0, exp_k>0 cancel),
// so out = (sigmoid(emb@Wq+bq) * (emb@Wv+bv)) @ Wo + bo.  Wk, bk, w are dead inputs.
//
// R8: R7's fp32-direct A staging, but software-pipelined one iteration ahead:
//   ds_write A(it) [no wait: drained at prev barrier2] ; GLDS B(it) ; barrier ;
//   issue A(it+1) loads ; MFMA loop (hides load latency) ; barrier [drains A(it+1)].
// R7 failed because A loads were consumed same-iteration (full vmcnt stall/iter).
// prep = weight transposes only. bt unchanged (R6 128x128).

typedef short bf16x8 __attribute__((ext_vector_type(8)));  // 8 bf16 = 4 VGPRs
typedef float f32x4  __attribute__((ext_vector_type(4)));

__device__ __forceinline__ short f2bf(float f) {  // RNE fp32 -> bf16
  union { float f; unsigned u; } x; x.f = f;
  unsigned r = x.u + 0x7fffu + ((x.u >> 16) & 1u);
  return (short)(r >> 16);
}

// pack two fp32 -> bf16 pair (round-half-up), one v_perm after two v_add
__device__ __forceinline__ unsigned pkbf(float f0, float f1) {
  unsigned a = __float_as_uint(f1) + 0x8000u;  // src0: bytes 4-7 of {s0:s1}
  unsigned b = __float_as_uint(f0) + 0x8000u;  // src1: bytes 0-3
  return __builtin_amdgcn_perm(a, b, 0x07060302u);  // [f0.hi16 | f1.hi16]
}

struct alignas(16) S8 { short v[8]; };

__device__ __forceinline__ S8 pack8(float4 x, float4 y) {
  union { unsigned d[4]; S8 s; } u;
  u.d[0] = pkbf(x.x, x.y); u.d[1] = pkbf(x.z, x.w);
  u.d[2] = pkbf(y.x, y.y); u.d[3] = pkbf(y.z, y.w);
  return u.s;
}

#define GLDS(g, l) \
  __builtin_amdgcn_global_load_lds((const __attribute__((address_space(1))) void*)(g), \
                                   (__attribute__((address_space(3))) void*)(l), 16, 0, 0)

// ---- Phase 0: transpose+cast the three 1024x1024 weights (grid 3072, 1 tile/block) ----
__global__ __launch_bounds__(256) void prep_kernel(
    const float* __restrict__ Wq, const float* __restrict__ Wv, const float* __restrict__ Wo,
    short* __restrict__ WqvT, short* __restrict__ WoT) {
  __shared__ float tr[32 * 33];
  const int t = threadIdx.x;
  const int z = blockIdx.x;
  const float* in = (z < 1024) ? Wq : (z < 2048) ? Wv : Wo;
  short* op = (z < 1024) ? WqvT : (z < 2048) ? (WqvT + 1048576) : WoT;
  const int ti = z & 1023;
  const int bx = (ti & 31) * 32, by = (ti >> 5) * 32;
  const int tx = t & 31, ty = t >> 5;
#pragma unroll
  for (int i = 0; i < 32; i += 8)
    tr[(ty + i) * 33 + tx] = in[(size_t)(by + ty + i) * 1024 + bx + tx];
  __syncthreads();
#pragma unroll
  for (int i = 0; i < 32; i += 8)
    op[(size_t)(bx + ty + i) * 1024 + by + tx] = f2bf(tr[tx * 33 + ty + i]);
}

// ---- Phase 1: X = sigmoid(emb@WqT+bq) * (emb@WvT+bv), bf16. BK=64, pipelined A. ----
// Block 128x64, 4 waves of 64x32 (q and v). grid (64,16)=1024.
__global__ __launch_bounds__(256) void gemm_qv_kernel(
    const float* __restrict__ A,      // emb fp32 [8192][1024]
    const short* __restrict__ BT,     // [WqT|WvT] bf16 [2048][1024]
    const float* __restrict__ bq, const float* __restrict__ bv, short* __restrict__ X) {
  __shared__ short As[128 * 64];  // 16 KiB
  __shared__ short Bqs[64 * 64];  // 8 KiB
  __shared__ short Bvs[64 * 64];  // 8 KiB
  const int t = threadIdx.x;
  const int lane = t & 63;
  const int w = t >> 6;
  const int l16 = lane & 15;
  const int quad = lane >> 4;
  const int bm = blockIdx.x * 128;
  const int bn = blockIdx.y * 64;
  const int wm = (w & 1) * 64;
  const int wn = (w >> 1) * 32;

  // A staging (per-lane): thread owns bf16 chunk (rows r8+{0,32,64,96}, slot t&7),
  // holding global chunk ch = (t&7)^(r8&7)  [same swizzle as R5]
  const int r8 = t >> 3;
  const int ch = (t & 7) ^ (r8 & 7);
  const float* gA0 = A + (size_t)(bm + r8) * 1024 + ch * 8;
  const float* gA1 = gA0 + 32 * 1024;
  const float* gA2 = gA0 + 64 * 1024;
  const float* gA3 = gA0 + 96 * 1024;
  short* sA = As + r8 * 64 + (t & 7) * 8;  // per-lane ds_write dest (scatter OK)

  // B staging via GLDS (wave-uniform LDS base)
  const int swe = ch * 8;
  const short* pBq0 = BT + (size_t)(bn + r8) * 1024 + swe;
  const short* pBq1 = pBq0 + 32 * 1024;
  const short* pBv0 = BT + (size_t)(1024 + bn + r8) * 1024 + swe;
  const short* pBv1 = pBv0 + 32 * 1024;
  short* lBq = Bqs + w * 512;
  short* lBv = Bvs + w * 512;

  // fragment bases (loop-invariant; i handled by ds imm offsets)
  const int qsw0 = (quad ^ (l16 & 7)) * 8;        // k-half 0: chunk quad
  const int qsw1 = ((quad + 4) ^ (l16 & 7)) * 8;  // k-half 1: chunk quad+4
  const short* fA0 = As + (wm + l16) * 64 + qsw0;
  const short* fA1 = As + (wm + l16) * 64 + qsw1;
  const short* fq0 = Bqs + (wn + l16) * 64 + qsw0;
  const short* fq1 = Bqs + (wn + l16) * 64 + qsw1;
  const short* fv0 = Bvs + (wn + l16) * 64 + qsw0;
  const short* fv1 = Bvs + (wn + l16) * 64 + qsw1;

  f32x4 accq[4][2] = {};
  f32x4 accv[4][2] = {};

  // prologue: load A(0) into regs
  float4 a0 = *(const float4*)(gA0), a0b = *(const float4*)(gA0 + 4);
  float4 a1 = *(const float4*)(gA1), a1b = *(const float4*)(gA1 + 4);
  float4 a2 = *(const float4*)(gA2), a2b = *(const float4*)(gA2 + 4);
  float4 a3 = *(const float4*)(gA3), a3b = *(const float4*)(gA3 + 4);

  for (int it = 0; it < 16; ++it) {
    // pack + ds_write A(it): regs were drained by prev iteration's barrier2
    // (prologue loads wait here once at it=0)
    *(S8*)(sA)        = pack8(a0, a0b);
    *(S8*)(sA + 2048) = pack8(a1, a1b);
    *(S8*)(sA + 4096) = pack8(a2, a2b);
    *(S8*)(sA + 6144) = pack8(a3, a3b);
    GLDS(pBq0, lBq); GLDS(pBq1, lBq + 2048);
    GLDS(pBv0, lBv); GLDS(pBv1, lBv + 2048);
    pBq0 += 64; pBq1 += 64; pBv0 += 64; pBv1 += 64;
    __syncthreads();  // drains B GLDS + ds_writes

    // issue A(it+1) prefetch AFTER the barrier (can't hoist above it);
    // latency hidden under the MFMA loop, drained at barrier2.
    if (it < 15) {
      gA0 += 64; gA1 += 64; gA2 += 64; gA3 += 64;
      a0 = *(const float4*)(gA0); a0b = *(const float4*)(gA0 + 4);
      a1 = *(const float4*)(gA1); a1b = *(const float4*)(gA1 + 4);
      a2 = *(const float4*)(gA2); a2b = *(const float4*)(gA2 + 4);
      a3 = *(const float4*)(gA3); a3b = *(const float4*)(gA3 + 4);
    }

#pragma unroll
    for (int h = 0; h < 2; h++) {
      const short* fA = h ? fA1 : fA0;
      const short* fq = h ? fq1 : fq0;
      const short* fv = h ? fv1 : fv0;
      bf16x8 av[4], bqf[2], bvf[2];
#pragma unroll
      for (int i = 0; i < 4; i++) av[i] = *(const bf16x8*)(fA + i * 1024);
#pragma unroll
      for (int j = 0; j < 2; j++) {
        bqf[j] = *(const bf16x8*)(fq + j * 1024);
        bvf[j] = *(const bf16x8*)(fv + j * 1024);
      }
#pragma unroll
      for (int i = 0; i < 4; i++)
#pragma unroll
        for (int j = 0; j < 2; j++) {
          accq[i][j] = __builtin_amdgcn_mfma_f32_16x16x32_bf16(av[i], bqf[j], accq[i][j], 0, 0, 0);
          accv[i][j] = __builtin_amdgcn_mfma_f32_16x16x32_bf16(av[i], bvf[j], accv[i][j], 0, 0, 0);
        }
    }
    __syncthreads();  // protects LDS; also drains A(it+1) loads (already complete)
  }

  // epilogue: C/D layout col=lane&15, row=(lane>>4)*4+reg  [m89/m91-verified]
#pragma unroll
  for (int j = 0; j < 2; j++) {
    int col = bn + wn + j * 16 + l16;
    float bql = bq[col], bvl = bv[col];
#pragma unroll
    for (int i = 0; i < 4; i++)
#pragma unroll
      for (int r = 0; r < 4; r++) {
        int row = bm + wm + i * 16 + quad * 4 + r;
        float q = accq[i][j][r] + bql;
        float v = accv[i][j][r] + bvl;
        float s = 1.0f / (1.0f + __expf(-q));
        X[(size_t)row * 1024 + col] = f2bf(s * v);
      }
  }
}

// ---- Phase 2: out = X @ WoT^T + bo, fp32. 128x128 tile, BK=64, grid (64,8). ----
__global__ __launch_bounds__(256) void gemm_bt_kernel(
    const short* __restrict__ A, const short* __restrict__ BT, float* __restrict__ C,
    const float* __restrict__ bias) {
  __shared__ short As[128 * 64];  // 16 KiB
  __shared__ short Bs[128 * 64];  // 16 KiB
  const int t = threadIdx.x;
  const int lane = t & 63;
  const int w = t >> 6;
  const int l16 = lane & 15;
  const int quad = lane >> 4;
  const int bm = blockIdx.x * 128;
  const int bn = blockIdx.y * 128;
  const int wm = (w & 1) * 64;
  const int wn = (w >> 1) * 64;

  const int r8 = t >> 3;
  const int swe = ((t & 7) ^ (r8 & 7)) * 8;
  const short* pA0 = A + (size_t)(bm + r8) * 1024 + swe;
  const short* pA1 = pA0 + 32 * 1024;
  const short* pA2 = pA0 + 64 * 1024;
  const short* pA3 = pA0 + 96 * 1024;
  const short* pB0 = BT + (size_t)(bn + r8) * 1024 + swe;
  const short* pB1 = pB0 + 32 * 1024;
  const short* pB2 = pB0 + 64 * 1024;
  const short* pB3 = pB0 + 96 * 1024;
  short* lA = As + w * 512;
  short* lB = Bs + w * 512;

  const int qsw0 = (quad ^ (l16 & 7)) * 8;
  const int qsw1 = ((quad + 4) ^ (l16 & 7)) * 8;
  const short* fA0 = As + (wm + l16) * 64 + qsw0;
  const short* fA1 = As + (wm + l16) * 64 + qsw1;
  const short* fB0 = Bs + (wn + l16) * 64 + qsw0;
  const short* fB1 = Bs + (wn + l16) * 64 + qsw1;

  f32x4 acc[4][4] = {};

  for (int it = 0; it < 16; ++it) {
    GLDS(pA0, lA); GLDS(pA1, lA + 2048); GLDS(pA2, lA + 4096); GLDS(pA3, lA + 6144);
    GLDS(pB0, lB); GLDS(pB1, lB + 2048); GLDS(pB2, lB + 4096); GLDS(pB3, lB + 6144);
    pA0 += 64; pA1 += 64; pA2 += 64; pA3 += 64;
    pB0 += 64; pB1 += 64; pB2 += 64; pB3 += 64;
    __syncthreads();

#pragma unroll
    for (int h = 0; h < 2; h++) {
      const short* fA = h ? fA1 : fA0;
      const short* fB = h ? fB1 : fB0;
      bf16x8 av[4], bw[4];
#pragma unroll
      for (int i = 0; i < 4; i++) av[i] = *(const bf16x8*)(fA + i * 1024);
#pragma unroll
      for (int j = 0; j < 4; j++) bw[j] = *(const bf16x8*)(fB + j * 1024);
#pragma unroll
      for (int i = 0; i < 4; i++)
#pragma unroll
        for (int j = 0; j < 4; j++)
          acc[i][j] = __builtin_amdgcn_mfma_f32_16x16x32_bf16(av[i], bw[j], acc[i][j], 0, 0, 0);
    }
    __syncthreads();
  }

#pragma unroll
  for (int j = 0; j < 4; j++) {
    int col = bn + wn + j * 16 + l16;
    float bl = bias[col];
#pragma unroll
    for (int i = 0; i < 4; i++)
#pragma unroll
      for (int r = 0; r < 4; r++) {
        int row = bm + wm + i * 16 + quad * 4 + r;
        C[(size_t)row * 1024 + col] = acc[i][j][r] + bl;
      }
  }
}

extern "C" void kernel_launch(void* const* d_in, const int* in_sizes, int n_in,
                              void* d_out, int out_size, void* d_ws, size_t ws_size,
                              hipStream_t stream) {
  const float* emb = (const float*)d_in[0];
  const float* Wq  = (const float*)d_in[1];
  const float* bq  = (const float*)d_in[2];
  // d_in[3]=Wk, d_in[4]=bk, d_in[7]=w are mathematically dead (they cancel)
  const float* Wv  = (const float*)d_in[5];
  const float* bv  = (const float*)d_in[6];
  const float* Wo  = (const float*)d_in[8];
  const float* bo  = (const float*)d_in[9];
  float* out = (float*)d_out;

  // workspace layout (bytes)
  char* ws = (char*)d_ws;
  short* X    = (short*)(ws);                 // 8192*1024 bf16 = 16 MiB
  short* WqvT = (short*)(ws + 16777216);      // [WqT | WvT] 2048*1024 = 4 MiB
  short* WoT  = (short*)(ws + 20971520);      // 1024*1024 = 2 MiB
  // total: 23,068,672 bytes

  prep_kernel<<<3072, 256, 0, stream>>>(Wq, Wv, Wo, WqvT, WoT);
  gemm_qv_kernel<<<dim3(64, 16), 256, 0, stream>>>(emb, WqvT, bq, bv, X);
  gemm_bt_kernel<<<dim3(64, 8), 256, 0, stream>>>(X, WoT, out, bo);
}